// Round 13
// baseline (117.546 us; speedup 1.0000x reference)
//
#include <hip/hip_runtime.h>

// PreHTSK fused, MFMA edition v10 — 2 launches.
// Kernel A (prep): pack(gamma*W -> bf16 MFMA fragments, G/Bb partials, Wtail)
//                  + frs (firing levels, softmax, LN stats, X->bf16) + out-zero.
// Kernel B: 1024 gemm blocks (32-row tiles, half-rule 16KB dbuf, 4 blocks/CU,
//           bt-minor XCD-local atomics)  +  64 finalize blocks (one per o:
//           coalesced G/Bb reduce, then atomicAdd affine column into out).
// out[b,o] = rstd[b]*(S+T) + Bb[o] - mur[b]*G[o]
//   S = sum_r frs[b,r] * sum_i X[b,i]*gamma[r*256+i]*W[o,r*256+i]
//   T = sum_r frs[b,r] * Wtail[r][o]
// LN closed-form: mu=(Sx+1)/D, E[f^2]=Q*(Sx2+1)/D, Q=sum frs^2 (sum frs = 1).

#define B_    2048
#define IN_   256
#define NR_   128
#define OUT_  64
#define D_    32896
#define XP_   32768
#define KSPLIT 16   // rule-groups; 8 rules per gemm block

typedef short s16x8 __attribute__((ext_vector_type(8)));
typedef float f32x4 __attribute__((ext_vector_type(4)));

__device__ __forceinline__ unsigned short bfc(float f) {
  union { float f; unsigned int u; } v; v.f = f;
  unsigned int r = (v.u + 0x7fffu + ((v.u >> 16) & 1u)) >> 16;  // RNE
  return (unsigned short)r;
}

__device__ __forceinline__ void gload_lds16(const void* g, void* l) {
  __builtin_amdgcn_global_load_lds(
      (const __attribute__((address_space(1))) void*)g,
      (__attribute__((address_space(3))) void*)l, 16, 0, 0);
}

// ================= Kernel A (512 blocks, 512 thr):
//   0..255   pack: r = bid>>1, ic-half = bid&1. Bpack fragments (bf16 gamma*W),
//            Gpart/Bpart partials ([o][1024] transposed), Wtail (half==1).
//   256..511 frs: zero own out-slice; firing levels + softmax + LN stats + X->bf16.
__global__ __launch_bounds__(512) void prep_frs_kernel(
    const float* __restrict__ X, const float* __restrict__ centers,
    const float* __restrict__ sigmas, const float* __restrict__ W,
    const float* __restrict__ gamma, const float* __restrict__ beta,
    unsigned short* __restrict__ Bpack, float* __restrict__ Gpart,
    float* __restrict__ Bpart, float* __restrict__ Wtail,
    float* __restrict__ frs, float* __restrict__ rstdO,
    float* __restrict__ murO, unsigned short* __restrict__ Xbf,
    float* __restrict__ out) {
  __shared__ float Wlds[64][68];      // pack path
  __shared__ float Xs[8][256];        // frs path
  __shared__ float pre[4][8][128];
  int tid = threadIdx.x;

  if (blockIdx.x < 256) {             // ---- pack path
    int r = blockIdx.x >> 1, half = blockIdx.x & 1;
    int lane = tid & 63, w = tid >> 6;
    int kcl = w & 1, ct = w >> 1;     // wave handles (k-half, col-tile)
    int o_f = ct * 16 + (lane & 15);
    if (half == 1 && tid < 64) {      // Wtail[r][o] (scattered, 64 loads)
      int d = XP_ + r;
      Wtail[r * 64 + tid] = W[(size_t)tid * D_ + d] * gamma[d];
    }
    for (int ici = 0; ici < 2; ici++) {
      int ic = half * 2 + ici;
      // coalesced: W[o][r*256+ic*64 .. +64) -> Wlds[o][0..64)
      for (int v = tid; v < 1024; v += 512) {
        int o = v >> 4, c4 = v & 15;
        float4 x = *(const float4*)&W[(size_t)o * D_ + r * 256 + ic * 64 + c4 * 4];
        *(float4*)&Wlds[o][c4 * 4] = x;
      }
      __syncthreads();
      int kc = ic * 2 + kcl;
      int il = kcl * 32 + (lane >> 4) * 8;
      int dg = r * 256 + ic * 64 + il;
      float4 g0  = *(const float4*)&gamma[dg];
      float4 g1  = *(const float4*)&gamma[dg + 4];
      float4 be0 = *(const float4*)&beta[dg];
      float4 be1 = *(const float4*)&beta[dg + 4];
      float4 w0 = *(const float4*)&Wlds[o_f][il];
      float4 w1 = *(const float4*)&Wlds[o_f][il + 4];
      unsigned int u[4];
      u[0] = bfc(w0.x * g0.x) | ((unsigned int)bfc(w0.y * g0.y) << 16);
      u[1] = bfc(w0.z * g0.z) | ((unsigned int)bfc(w0.w * g0.w) << 16);
      u[2] = bfc(w1.x * g1.x) | ((unsigned int)bfc(w1.y * g1.y) << 16);
      u[3] = bfc(w1.z * g1.z) | ((unsigned int)bfc(w1.w * g1.w) << 16);
      int rb = r * 8 + kc;
      *(uint4*)&Bpack[((size_t)(rb * 4 + ct) * 64 + lane) * 8] = make_uint4(u[0], u[1], u[2], u[3]);
      float gs = w0.x*g0.x + w0.y*g0.y + w0.z*g0.z + w0.w*g0.w
               + w1.x*g1.x + w1.y*g1.y + w1.z*g1.z + w1.w*g1.w;
      float bs = w0.x*be0.x + w0.y*be0.y + w0.z*be0.z + w0.w*be0.w
               + w1.x*be1.x + w1.y*be1.y + w1.z*be1.z + w1.w*be1.w;
      gs += __shfl_xor(gs, 16); gs += __shfl_xor(gs, 32);
      bs += __shfl_xor(bs, 16); bs += __shfl_xor(bs, 32);
      if ((lane >> 4) == 0) {         // transposed: [o][rb] for coalesced reduce
        Gpart[(size_t)o_f * 1024 + rb] = gs;
        Bpart[(size_t)o_f * 1024 + rb] = bs;
      }
      __syncthreads();
    }
    return;
  }

  // ---- frs path
  int bt = blockIdx.x - 256;          // 0..255
  int b0 = bt * 8;
  {
    // zero this block's out slice: 8 rows x 64 = 512 floats = 128 float4
    if (tid < 128) {
      float4 z = {0.f, 0.f, 0.f, 0.f};
      ((float4*)out)[bt * 128 + tid] = z;
    }
    int row = tid >> 6, c4 = (tid & 63) * 4;
    float4 x = *(const float4*)&X[(size_t)(b0 + row) * 256 + c4];
    *(float4*)&Xs[row][c4] = x;
    uint2 p;
    p.x = bfc(x.x) | ((unsigned int)bfc(x.y) << 16);
    p.y = bfc(x.z) | ((unsigned int)bfc(x.w) << 16);
    *(uint2*)&Xbf[(size_t)(b0 + row) * 256 + c4] = p;
  }
  __syncthreads();
  int r = tid & 127, h = tid >> 7;
  float acc[8] = {0.f,0.f,0.f,0.f,0.f,0.f,0.f,0.f};
  int i0 = h * 64;
#pragma unroll 4
  for (int i = i0; i < i0 + 64; i++) {
    float sg = sigmas[i * NR_ + r];
    float c  = centers[i * NR_ + r];
    float s  = __fdividef(0.5f, sg * sg) + 1e-8f;
#pragma unroll
    for (int row = 0; row < 8; row++) {
      float d = Xs[row][i] - c;
      acc[row] = fmaf(d * s, d, acc[row]);
    }
  }
#pragma unroll
  for (int row = 0; row < 8; row++) pre[h][row][r] = acc[row];
  __syncthreads();
  int wv = tid >> 6, lane = tid & 63;
  float v0 = pre[0][wv][lane]      + pre[1][wv][lane]      + pre[2][wv][lane]      + pre[3][wv][lane];
  float v1 = pre[0][wv][lane + 64] + pre[1][wv][lane + 64] + pre[2][wv][lane + 64] + pre[3][wv][lane + 64];
  v0 *= -(1.f / 256.f);
  v1 *= -(1.f / 256.f);
  float m = fmaxf(v0, v1);
  for (int st = 32; st; st >>= 1) m = fmaxf(m, __shfl_xor(m, st));
  float e0 = __expf(v0 - m), e1 = __expf(v1 - m);
  float s = e0 + e1;
  for (int st = 32; st; st >>= 1) s += __shfl_xor(s, st);
  float invs = 1.f / s;
  float f0 = e0 * invs, f1 = e1 * invs;
  int b = b0 + wv;
  frs[(size_t)b * 128 + lane]      = f0;
  frs[(size_t)b * 128 + 64 + lane] = f1;
  float q = f0 * f0 + f1 * f1;
  for (int st = 32; st; st >>= 1) q += __shfl_xor(q, st);
  float sx = 0.f, sx2 = 0.f;
#pragma unroll
  for (int j = 0; j < 4; j++) {
    float x = Xs[wv][lane * 4 + j];
    sx += x; sx2 = fmaf(x, x, sx2);
  }
  for (int st = 32; st; st >>= 1) { sx += __shfl_xor(sx, st); sx2 += __shfl_xor(sx2, st); }
  if (lane == 0) {
    float mu  = (sx + 1.f) / (float)D_;
    float msq = q * (sx2 + 1.f) / (float)D_;
    float var = msq - mu * mu;
    float rs  = rsqrtf(var + 1e-5f);
    rstdO[b] = rs;
    murO[b]  = mu * rs;
  }
}

// ================= Kernel B (1088 blocks, 256 thr):
//  0..1023  gemm: bt = id&63 (32-row tile), ks = id>>6 (8 rules). Half-rule
//           (16 KB) LDS dbuf via global_load_lds; atomicAdd rstd*(S+T) into out.
//  1024..1087 finalize (o = id-1024): coalesced G/Bb reduce from Gpart/Bpart
//           (+tail +bias), then atomicAdd (Bb - mur[b]*G) column into out.
__global__ __launch_bounds__(256) void gemm_kernel(
    const unsigned short* __restrict__ Xbf, const unsigned short* __restrict__ Bpack,
    const float* __restrict__ frs, const float* __restrict__ rstd,
    const float* __restrict__ Wtail, const float* __restrict__ Gpart,
    const float* __restrict__ Bpart, const float* __restrict__ W,
    const float* __restrict__ gamma, const float* __restrict__ beta,
    const float* __restrict__ bias, const float* __restrict__ mur,
    float* __restrict__ out) {
  __shared__ unsigned short Blds[2][8192];    // 2 x 16KB
  __shared__ float frs_s[32][9];
  __shared__ float Wt_s[8][64];
  __shared__ float rstd_s[32];
  int tid = threadIdx.x;

  if (blockIdx.x >= 1024) {           // ---- finalize path (one block per o)
    int o = blockIdx.x - 1024;
    __shared__ float rg[256], rb[256];
    float gs = 0.f, bs = 0.f;
    for (int j = tid; j < 1024; j += 256) {   // coalesced: Gpart[o][j]
      gs += Gpart[(size_t)o * 1024 + j];
      bs += Bpart[(size_t)o * 1024 + j];
    }
    if (tid < 128) {                          // tail: contiguous over tid
      int d = XP_ + tid;
      float wt = W[(size_t)o * D_ + d];
      gs += wt * gamma[d];
      bs += wt * beta[d];
    }
    rg[tid] = gs; rb[tid] = bs;
    __syncthreads();
    for (int st = 128; st > 0; st >>= 1) {
      if (tid < st) { rg[tid] += rg[tid + st]; rb[tid] += rb[tid + st]; }
      __syncthreads();
    }
    float Go  = rg[0];
    float Bbo = rb[0] + bias[o];
    for (int b = tid; b < B_; b += 256)
      atomicAdd(&out[(size_t)b * OUT_ + o], Bbo - mur[b] * Go);
    return;
  }

  // ---- gemm path
  int bt = blockIdx.x & 63, ks = blockIdx.x >> 6;
  int lane = tid & 63, w = tid >> 6, wr = w & 1, wc = w >> 1;

  {   // frs_s: 32 rows x 8 rules, one entry per thread
    int row = tid >> 3, rr = tid & 7;
    frs_s[row][rr] = frs[(size_t)(bt * 32 + row) * NR_ + ks * 8 + rr];
  }
  for (int idx = tid; idx < 512; idx += 256) {      // coalesced 2KB
    int rr = idx >> 6, o = idx & 63;
    Wt_s[rr][o] = Wtail[(ks * 8 + rr) * 64 + o];
  }
  if (tid < 32) rstd_s[tid] = rstd[bt * 32 + tid];

  // X fragments in registers (16 rows x 256 k), reused across all 8 rules
  s16x8 xf[8];
  int browbase = bt * 32 + wr * 16;
  {
    const unsigned short* xp = Xbf + (size_t)(browbase + (lane & 15)) * 256 + (lane >> 4) * 8;
#pragma unroll
    for (int kc = 0; kc < 8; kc++)
      xf[kc] = *(const s16x8*)(xp + kc * 32);
  }

  // stage half 0 (rule 0, kc 0..3) into buf 0: 16KB = 4 x 16B per thread
  const char* bbase = (const char*)Bpack + (size_t)ks * 8 * 32768;
  char* lbase = (char*)&Blds[0][0];
  {
#pragma unroll
    for (int p = 0; p < 4; p++)
      gload_lds16(bbase + tid * 16 + p * 4096, lbase + w * 1024 + p * 4096);
  }
  __syncthreads();   // drains vmcnt(0): buf0 + LDS tables ready

  f32x4 S0 = {0.f,0.f,0.f,0.f}, S1 = S0;
  f32x4 P0 = S0, P1 = S0;

  for (int h = 0; h < 16; h++) {            // h = rule*2 + khalf
    if (h < 15) {    // stage next half into the other buffer
      const char* src = bbase + (size_t)(h + 1) * 16384;
      char* ldst = lbase + ((h + 1) & 1) * 16384;
#pragma unroll
      for (int p = 0; p < 4; p++)
        gload_lds16(src + tid * 16 + p * 4096, ldst + w * 1024 + p * 4096);
    }
    const unsigned short* bb = &Blds[h & 1][0];
    int kbase = (h & 1) * 4;                // global kc offset of this half
#pragma unroll
    for (int kcl = 0; kcl < 4; kcl++) {
      s16x8 bf0 = *(const s16x8*)(bb + (size_t)((kcl * 4 + wc * 2 + 0) * 64 + lane) * 8);
      s16x8 bf1 = *(const s16x8*)(bb + (size_t)((kcl * 4 + wc * 2 + 1) * 64 + lane) * 8);
      P0 = __builtin_amdgcn_mfma_f32_16x16x32_bf16(xf[kbase + kcl], bf0, P0, 0, 0, 0);
      P1 = __builtin_amdgcn_mfma_f32_16x16x32_bf16(xf[kbase + kcl], bf1, P1, 0, 0, 0);
    }
    if (h & 1) {     // rule complete: fold with f32 frs, reset P
      int rr = h >> 1;
#pragma unroll
      for (int q = 0; q < 4; q++) {
        float fv = frs_s[wr * 16 + (lane >> 4) * 4 + q][rr];
        S0[q] += fv * P0[q];  S1[q] += fv * P1[q];
        P0[q] = 0.f; P1[q] = 0.f;
      }
    }
    __syncthreads();   // next buffer staged
  }

  // tail GEMV + rstd scale + atomic accumulate into out
  int o0 = wc * 32 + (lane & 15);
#pragma unroll
  for (int q = 0; q < 4; q++) {
    int lr = wr * 16 + (lane >> 4) * 4 + q;
    float t0 = 0.f, t1 = 0.f;
#pragma unroll
    for (int rr = 0; rr < 8; rr++) {
      float f = frs_s[lr][rr];
      t0 = fmaf(f, Wt_s[rr][o0],      t0);
      t1 = fmaf(f, Wt_s[rr][o0 + 16], t1);
    }
    float r0 = rstd_s[lr];
    size_t base = (size_t)(bt * 32 + lr) * OUT_;
    atomicAdd(&out[base + o0],      r0 * (S0[q] + t0));
    atomicAdd(&out[base + o0 + 16], r0 * (S1[q] + t1));
  }
}

extern "C" void kernel_launch(void* const* d_in, const int* in_sizes, int n_in,
                              void* d_out, int out_size, void* d_ws, size_t ws_size,
                              hipStream_t stream) {
  const float* X       = (const float*)d_in[0];
  const float* centers = (const float*)d_in[1];
  const float* sigmas  = (const float*)d_in[2];
  const float* gamma   = (const float*)d_in[3];
  const float* beta    = (const float*)d_in[4];
  const float* W       = (const float*)d_in[5];
  const float* bias    = (const float*)d_in[6];
  float* out = (float*)d_out;

  char* ws = (char*)d_ws;
  float* rstd          = (float*)(ws);                     // 8 KB
  float* mur           = (float*)(ws + 8192);              // 8 KB
  float* frs           = (float*)(ws + 16384);             // 1 MB
  unsigned short* Xbf  = (unsigned short*)(ws + 1064960);  // 1 MB
  unsigned short* Bpack= (unsigned short*)(ws + 2113536);  // 4 MB
  float* Gpart         = (float*)(ws + 6307840);           // 256 KB ([64][1024])
  float* Bpart         = (float*)(ws + 6569984);           // 256 KB
  float* Wtail         = (float*)(ws + 6832128);           // 32 KB (total ~6.9 MB)

  hipLaunchKernelGGL(prep_frs_kernel, dim3(512), dim3(512), 0, stream,
                     X, centers, sigmas, W, gamma, beta,
                     Bpack, Gpart, Bpart, Wtail, frs, rstd, mur, Xbf, out);
  hipLaunchKernelGGL(gemm_kernel, dim3(1088), dim3(256), 0, stream,
                     Xbf, Bpack, frs, rstd, Wtail, Gpart, Bpart,
                     W, gamma, beta, bias, mur, out);
}